// Round 7
// baseline (259.792 us; speedup 1.0000x reference)
//
#include <hip/hip_runtime.h>
#include <hip/hip_bf16.h>

typedef __attribute__((ext_vector_type(4))) float float4v;
typedef __attribute__((ext_vector_type(8))) short short8v;
typedef __attribute__((ext_vector_type(4))) unsigned int uint4v;

__device__ __forceinline__ unsigned short f2bf(float f) {
  __hip_bfloat16 h = __float2bfloat16(f);   // HW RNE cvt
  return __builtin_bit_cast(unsigned short, h);
}
__device__ __forceinline__ unsigned int pk2(float a, float b) {
  return (unsigned int)f2bf(a) | ((unsigned int)f2bf(b) << 16);
}

// Fused one-time pass: feat f32 -> bf16 table (halves gather bytes) + new_point copy.
__global__ __launch_bounds__(256) void td_prep(const float* __restrict__ feat,
                                               unsigned short* __restrict__ fb,
                                               int total8,
                                               const float* __restrict__ point,
                                               const int* __restrict__ sidx,
                                               float* __restrict__ newp, int m,
                                               int prepBlocks) {
  if ((int)blockIdx.x < prepBlocks) {
    int i = blockIdx.x * 256 + threadIdx.x;
    if (i < total8) {
      const float4v a = *(const float4v*)(feat + (size_t)i * 8);
      const float4v c = *(const float4v*)(feat + (size_t)i * 8 + 4);
      uint4v u;
      u[0] = pk2(a[0], a[1]); u[1] = pk2(a[2], a[3]);
      u[2] = pk2(c[0], c[1]); u[3] = pk2(c[2], c[3]);
      *(uint4v*)(fb + (size_t)i * 8) = u;
    }
  } else {
    int i = (blockIdx.x - prepBlocks) * 256 + threadIdx.x;
    if (i < m) {
      unsigned s = (unsigned)sidx[i];
      newp[(size_t)i * 3 + 0] = point[s * 3u + 0];
      newp[(size_t)i * 3 + 1] = point[s * 3u + 1];
      newp[(size_t)i * 3 + 2] = point[s * 3u + 2];
    }
  }
}

// td_main: tile = 4 sampled points (64 rows) x K=96 (feat 0..63 | xyz 64..66 | 0).
// Register software-pipeline: tile t+1's gathers issued at top of iter t from
// the bf16 table, parked in regs across MFMA+epilogue, written to LDS after B2.
// 8 blocks/CU requested: all blocks co-resident in one generation.
__global__ __launch_bounds__(256, 8) void td_main(
    const float* __restrict__ point, const float* __restrict__ feat,
    const unsigned short* __restrict__ fb, const float* __restrict__ W,
    const float* __restrict__ gamma,
    const int* __restrict__ sample_idx, const int* __restrict__ knn_idx,
    float* __restrict__ ymax_out, float* __restrict__ ymin_out,
    float* __restrict__ partials, int nTiles, int has_ymin, int use_fb)
{
  __shared__ __align__(16) unsigned short A[64 * 104];   // 13312 B
  __shared__ int knn_lds[2][64];

  const int tid  = threadIdx.x;
  const int lane = tid & 63;
  const int wv   = tid >> 6;        // wave -> output channels wv*32..+31
  const int l15  = lane & 15;
  const int lg   = lane >> 4;
  const int G    = gridDim.x;
  const int t0   = blockIdx.x;
  const int segs = (tid & 3) << 4;  // element offset of this thread's 16-elem segment

  // One-time: B fragments direct from global W (bf16-rounded), permuted K.
  short8v bfrag[2][3];
  #pragma unroll
  for (int ni = 0; ni < 2; ++ni) {
    const int d = wv * 32 + ni * 16 + l15;
    #pragma unroll
    for (int kk = 0; kk < 3; ++kk) {
      short8v bf;
      #pragma unroll
      for (int j = 0; j < 8; ++j) {
        int c = kk * 32 + (lg << 3) + j;
        float v = 0.f;
        if (c < 64)      v = W[(3 + c) * 128 + d];
        else if (c < 67) v = W[(c - 64) * 128 + d];
        bf[j] = (short)f2bf(v);
      }
      bfrag[ni][kk] = bf;
    }
  }
  // min-path only needed for channels with gamma<0 (sign(a)==sign(gamma))
  const float gva = gamma[wv * 32 + l15];
  const float gvb = gamma[wv * 32 + 16 + l15];
  const bool  do_min = has_ymin && (__ballot((gva < 0.f) || (gvb < 0.f)) != 0ull);

  const bool alive = (t0 < nTiles);
  if (alive && tid < 64) knn_lds[0][tid] = knn_idx[t0 * 64 + tid];
  __syncthreads();

  // pipeline registers
  uint4v h0 = {0,0,0,0}, h1 = {0,0,0,0};
  float qx = 0, qy = 0, qz = 0, sx = 0, sy = 0, sz = 0;
  int   si_a = 0, knn_next = 0;

  // tile t0 loads (dependent chain once, in prologue)
  if (alive) {
    const int grow = knn_lds[0][tid >> 2];
    if (use_fb) {
      const uint4v* src = (const uint4v*)(fb + ((size_t)grow << 6) + segs);
      h0 = src[0]; h1 = src[1];
    } else {
      const float* srcf = feat + ((size_t)grow << 6) + segs;
      float4v f0 = *(const float4v*)(srcf),     f1 = *(const float4v*)(srcf + 4);
      float4v f2 = *(const float4v*)(srcf + 8), f3 = *(const float4v*)(srcf + 12);
      h0[0] = pk2(f0[0], f0[1]); h0[1] = pk2(f0[2], f0[3]);
      h0[2] = pk2(f1[0], f1[1]); h0[3] = pk2(f1[2], f1[3]);
      h1[0] = pk2(f2[0], f2[1]); h1[1] = pk2(f2[2], f2[3]);
      h1[2] = pk2(f3[0], f3[1]); h1[3] = pk2(f3[2], f3[3]);
    }
    if (tid < 64) {
      const float* ps = point + (unsigned)knn_lds[0][tid] * 3u;
      qx = ps[0]; qy = ps[1]; qz = ps[2];
      int si = sample_idx[t0 * 4 + (tid >> 4)];
      const float* pp2 = point + (unsigned)si * 3u;
      sx = pp2[0]; sy = pp2[1]; sz = pp2[2];
    }
  }
  if (t0 + G < nTiles && tid < 64) {
    knn_lds[1][tid] = knn_idx[(t0 + G) * 64 + tid];
    si_a = sample_idx[(t0 + G) * 4 + (tid >> 4)];
  }

  // write A[t0] (incl. one-time zero of cols 72..95)
  if (alive) {
    unsigned short* dst = A + (tid >> 2) * 104 + segs;
    *(uint4v*)(dst)     = h0;
    *(uint4v*)(dst + 8) = h1;
    if (tid < 64) {
      uint4v u; u[0] = pk2(qx - sx, qy - sy); u[1] = pk2(qz - sz, 0.f);
      u[2] = 0u; u[3] = 0u;
      unsigned short* dx = A + tid * 104 + 64;
      *(uint4v*)(dx) = u;                         // cols 64..71
      uint4v zz = {0u, 0u, 0u, 0u};
      *(uint4v*)(dx + 8)  = zz;                   // cols 72..95: once
      *(uint4v*)(dx + 16) = zz;
      *(uint4v*)(dx + 24) = zz;
    }
  }

  float sum0 = 0.f, sum1 = 0.f, sq0 = 0.f, sq1 = 0.f;

  int b = 0;
  for (int t = t0; t < nTiles; t += G, b ^= 1) {
    __syncthreads();   // B1: A[t] ready; knn[b^1] (tile t+G) visible
    const int tn  = t + G;
    const int tnn = t + 2 * G;
    const bool have_next = (tn < nTiles);

    // issue tile t+1 loads into regs (fly across MFMA + epilogue)
    if (have_next) {
      const int grow = knn_lds[b ^ 1][tid >> 2];
      if (use_fb) {
        const uint4v* src = (const uint4v*)(fb + ((size_t)grow << 6) + segs);
        h0 = src[0]; h1 = src[1];
      } else {
        const float* srcf = feat + ((size_t)grow << 6) + segs;
        float4v f0 = *(const float4v*)(srcf),     f1 = *(const float4v*)(srcf + 4);
        float4v f2 = *(const float4v*)(srcf + 8), f3 = *(const float4v*)(srcf + 12);
        h0[0] = pk2(f0[0], f0[1]); h0[1] = pk2(f0[2], f0[3]);
        h0[2] = pk2(f1[0], f1[1]); h0[3] = pk2(f1[2], f1[3]);
        h1[0] = pk2(f2[0], f2[1]); h1[1] = pk2(f2[2], f2[3]);
        h1[2] = pk2(f3[0], f3[1]); h1[3] = pk2(f3[2], f3[3]);
      }
      if (tid < 64) {
        const float* ps = point + (unsigned)knn_lds[b ^ 1][tid] * 3u;
        qx = ps[0]; qy = ps[1]; qz = ps[2];
        const float* pp2 = point + (unsigned)si_a * 3u;  // si_a from last iter
        sx = pp2[0]; sy = pp2[1]; sz = pp2[2];
      }
    }
    // issue tile t+2 index loads
    if (tnn < nTiles && tid < 64) {
      knn_next = knn_idx[tnn * 64 + tid];
      si_a = sample_idx[tnn * 4 + (tid >> 4)];
    }

    // MFMA on A[t]
    float4v acc[4][2];
    #pragma unroll
    for (int mi = 0; mi < 4; ++mi) {
      acc[mi][0] = (float4v){0.f, 0.f, 0.f, 0.f};
      acc[mi][1] = (float4v){0.f, 0.f, 0.f, 0.f};
    }
    #pragma unroll
    for (int mi = 0; mi < 4; ++mi) {
      const unsigned short* ar = A + (mi * 16 + l15) * 104 + (lg << 3);
      short8v a0 = *(const short8v*)(ar);
      short8v a1 = *(const short8v*)(ar + 32);
      short8v a2 = *(const short8v*)(ar + 64);
      #pragma unroll
      for (int ni = 0; ni < 2; ++ni) {
        acc[mi][ni] = __builtin_amdgcn_mfma_f32_16x16x32_bf16(a0, bfrag[ni][0], acc[mi][ni], 0, 0, 0);
        acc[mi][ni] = __builtin_amdgcn_mfma_f32_16x16x32_bf16(a1, bfrag[ni][1], acc[mi][ni], 0, 0, 0);
        acc[mi][ni] = __builtin_amdgcn_mfma_f32_16x16x32_bf16(a2, bfrag[ni][2], acc[mi][ni], 0, 0, 0);
      }
    }

    // epilogue: stats + per-point max (min only if some gamma<0)
    float mx0[4], mx1[4], mn0[4], mn1[4];
    #pragma unroll
    for (int mi = 0; mi < 4; ++mi) {
      #pragma unroll
      for (int ni = 0; ni < 2; ++ni) {
        float4v v = acc[mi][ni];
        float s = (v[0] + v[1]) + (v[2] + v[3]);
        float q = fmaf(v[0], v[0], fmaf(v[1], v[1], fmaf(v[2], v[2], v[3] * v[3])));
        if (ni == 0) { sum0 += s; sq0 += q; } else { sum1 += s; sq1 += q; }
        float mx = fmaxf(fmaxf(v[0], v[1]), fmaxf(v[2], v[3]));
        mx = fmaxf(mx, __shfl_xor(mx, 16)); mx = fmaxf(mx, __shfl_xor(mx, 32));
        if (ni == 0) mx0[mi] = mx; else mx1[mi] = mx;
        if (do_min) {
          float mn = fminf(fminf(v[0], v[1]), fminf(v[2], v[3]));
          mn = fminf(mn, __shfl_xor(mn, 16)); mn = fminf(mn, __shfl_xor(mn, 32));
          if (ni == 0) mn0[mi] = mn; else mn1[mi] = mn;
        }
      }
    }
    {
      float vx0 = lg == 0 ? mx0[0] : lg == 1 ? mx0[1] : lg == 2 ? mx0[2] : mx0[3];
      float vx1 = lg == 0 ? mx1[0] : lg == 1 ? mx1[1] : lg == 2 ? mx1[2] : mx1[3];
      size_t obase = (size_t)(t * 4 + lg) * 128 + wv * 32 + l15;
      ymax_out[obase]      = vx0;
      ymax_out[obase + 16] = vx1;
      if (do_min) {
        float vn0 = lg == 0 ? mn0[0] : lg == 1 ? mn0[1] : lg == 2 ? mn0[2] : mn0[3];
        float vn1 = lg == 0 ? mn1[0] : lg == 1 ? mn1[1] : lg == 2 ? mn1[2] : mn1[3];
        if (gva < 0.f) ymin_out[obase]      = vn0;
        if (gvb < 0.f) ymin_out[obase + 16] = vn1;
      }
    }
    // park prefetched knn for t+2 (loads long completed)
    if (tnn < nTiles && tid < 64) knn_lds[b][tid] = knn_next;
    __syncthreads();   // B2: A[t] consumed

    // write A[t+1] from in-flight regs (cols 0..71; 72..95 stay zero)
    if (have_next) {
      unsigned short* dst = A + (tid >> 2) * 104 + segs;
      *(uint4v*)(dst)     = h0;
      *(uint4v*)(dst + 8) = h1;
      if (tid < 64) {
        uint4v u; u[0] = pk2(qx - sx, qy - sy); u[1] = pk2(qz - sz, 0.f);
        u[2] = 0u; u[3] = 0u;
        *(uint4v*)(A + tid * 104 + 64) = u;
      }
    }
  }

  // deterministic per-block partials
  sum0 += __shfl_xor(sum0, 16); sum0 += __shfl_xor(sum0, 32);
  sq0  += __shfl_xor(sq0, 16);  sq0  += __shfl_xor(sq0, 32);
  sum1 += __shfl_xor(sum1, 16); sum1 += __shfl_xor(sum1, 32);
  sq1  += __shfl_xor(sq1, 16);  sq1  += __shfl_xor(sq1, 32);
  if (lane < 16) {
    float* pp = partials + (size_t)blockIdx.x * 256;
    pp[wv * 32 + lane]            = sum0;
    pp[128 + wv * 32 + lane]      = sq0;
    pp[wv * 32 + 16 + lane]       = sum1;
    pp[128 + wv * 32 + 16 + lane] = sq1;
  }
}

// Parallel BN-stats fold: one block per channel.
__global__ __launch_bounds__(256) void td_stats(
    const float* __restrict__ partials,
    const float* __restrict__ gamma,
    const float* __restrict__ beta,
    float* __restrict__ ab, int G, float invN)
{
  __shared__ float ls[256], lq[256];
  const int d = blockIdx.x;
  const int t = threadIdx.x;
  float s = 0.f, q = 0.f;
  for (int g = t; g < G; g += 256) {
    s += partials[(size_t)g * 256 + d];
    q += partials[(size_t)g * 256 + 128 + d];
  }
  ls[t] = s; lq[t] = q;
  __syncthreads();
  for (int w = 128; w > 0; w >>= 1) {
    if (t < w) { ls[t] += ls[t + w]; lq[t] += lq[t + w]; }
    __syncthreads();
  }
  if (t == 0) {
    float mean = ls[0] * invN;
    float var  = fmaxf(lq[0] * invN - mean * mean, 0.f);
    float a = gamma[d] * rsqrtf(var + 1e-5f);
    float bb = beta[d] - mean * a;
    ab[d] = a;
    ab[128 + d] = bb;
  }
}

__global__ __launch_bounds__(256) void td_transform(
    float* __restrict__ outf, const float* __restrict__ ymin,
    const float* __restrict__ ab, int total4, int has_ymin)
{
  __shared__ float sab[256];
  __shared__ int s_anyneg;
  sab[threadIdx.x] = ab[threadIdx.x];
  if (threadIdx.x == 0) s_anyneg = 0;
  __syncthreads();
  if (threadIdx.x < 128 && sab[threadIdx.x] < 0.f) s_anyneg = 1;
  __syncthreads();
  const int need_min = has_ymin && s_anyneg;
  int stride = gridDim.x * blockDim.x;
  for (int i = blockIdx.x * blockDim.x + threadIdx.x; i < total4; i += stride) {
    float4v v = *(const float4v*)(outf + (size_t)i * 4);
    int d0 = (i * 4) & 127;
    if (need_min) {
      float4v mn = *(const float4v*)(ymin + (size_t)i * 4);
      #pragma unroll
      for (int j = 0; j < 4; ++j)
        if (sab[d0 + j] < 0.f) v[j] = mn[j];
    }
    #pragma unroll
    for (int j = 0; j < 4; ++j) {
      float z = fmaf(v[j], sab[d0 + j], sab[128 + d0 + j]);
      v[j] = z > 0.f ? z : 0.f;
    }
    *(float4v*)(outf + (size_t)i * 4) = v;
  }
}

extern "C" void kernel_launch(void* const* d_in, const int* in_sizes, int n_in,
                              void* d_out, int out_size, void* d_ws, size_t ws_size,
                              hipStream_t stream)
{
  const float* point = (const float*)d_in[0];
  const float* feat  = (const float*)d_in[1];
  const float* W     = (const float*)d_in[2];
  const float* gamma = (const float*)d_in[3];
  const float* beta  = (const float*)d_in[4];
  const int* sample_idx = (const int*)d_in[5];
  const int* knn_idx    = (const int*)d_in[6];

  const int m = in_sizes[5];            // 60000
  const int k = in_sizes[6] / m;        // 16
  const int nTiles = m / 4;             // 4 points (64 rows) per tile
  const int feat_elems = in_sizes[1];   // n * 64

  float* out  = (float*)d_out;
  float* newp = out;                    // (m,3)
  float* ymax = out + (size_t)m * 3;    // (m,128) pre-norm max, finished in-place

  int G = (nTiles + 7) / 8;             // 8 tiles per block; <=2048 => one generation
  if (G > 2048) G = 2048;
  if (G < 1) G = 1;

  // ws layout: [ab 1KB][partials G*1KB][feat_bf16][ymin if it fits]
  char* ws = (char*)d_ws;
  float* ab = (float*)ws;
  float* partials = (float*)(ws + 1024);
  size_t fb_off = 1024 + (size_t)G * 1024;
  size_t fb_bytes = (size_t)feat_elems * 2;
  int use_fb = (ws_size >= fb_off + fb_bytes) ? 1 : 0;
  unsigned short* fb = (unsigned short*)(ws + fb_off);
  size_t ymin_off = fb_off + (use_fb ? fb_bytes : 0);
  int has_ymin = (ws_size >= ymin_off + (size_t)m * 512) ? 1 : 0;
  float* ymin = (float*)(ws + ymin_off);

  {
    int total8 = use_fb ? feat_elems / 8 : 0;
    int prepBlocks = (total8 + 255) / 256;
    int npBlocks = (m + 255) / 256;
    td_prep<<<prepBlocks + npBlocks, 256, 0, stream>>>(
        feat, fb, total8, point, sample_idx, newp, m, prepBlocks);
  }
  td_main<<<G, 256, 0, stream>>>(point, feat, fb, W, gamma, sample_idx, knn_idx,
                                 ymax, ymin, partials, nTiles, has_ymin, use_fb);
  float invN = 1.0f / ((float)m * (float)k);
  td_stats<<<128, 256, 0, stream>>>(partials, gamma, beta, ab, G, invN);
  td_transform<<<2048, 256, 0, stream>>>(ymax, ymin, ab, m * 128 / 4, has_ymin);
}

// Round 8
// 166.266 us; speedup vs baseline: 1.5625x; 1.5625x over previous
//
#include <hip/hip_runtime.h>
#include <hip/hip_bf16.h>

typedef __attribute__((ext_vector_type(4))) float float4v;
typedef __attribute__((ext_vector_type(8))) short short8v;
typedef __attribute__((ext_vector_type(4))) unsigned int uint4v;

__device__ __forceinline__ unsigned short f2bf(float f) {
  __hip_bfloat16 h = __float2bfloat16(f);   // HW RNE cvt
  return __builtin_bit_cast(unsigned short, h);
}
__device__ __forceinline__ unsigned int pk2(float a, float b) {
  return (unsigned int)f2bf(a) | ((unsigned int)f2bf(b) << 16);
}

// Fused one-time pass: feat f32 -> bf16 table (halves gather bytes) + new_point copy.
__global__ __launch_bounds__(256) void td_prep(const float* __restrict__ feat,
                                               unsigned short* __restrict__ fb,
                                               int total8,
                                               const float* __restrict__ point,
                                               const int* __restrict__ sidx,
                                               float* __restrict__ newp, int m,
                                               int prepBlocks) {
  if ((int)blockIdx.x < prepBlocks) {
    int i = blockIdx.x * 256 + threadIdx.x;
    if (i < total8) {
      const float4v a = *(const float4v*)(feat + (size_t)i * 8);
      const float4v c = *(const float4v*)(feat + (size_t)i * 8 + 4);
      uint4v u;
      u[0] = pk2(a[0], a[1]); u[1] = pk2(a[2], a[3]);
      u[2] = pk2(c[0], c[1]); u[3] = pk2(c[2], c[3]);
      *(uint4v*)(fb + (size_t)i * 8) = u;
    }
  } else {
    int i = (blockIdx.x - prepBlocks) * 256 + threadIdx.x;
    if (i < m) {
      unsigned s = (unsigned)sidx[i];
      newp[(size_t)i * 3 + 0] = point[s * 3u + 0];
      newp[(size_t)i * 3 + 1] = point[s * 3u + 1];
      newp[(size_t)i * 3 + 2] = point[s * 3u + 2];
    }
  }
}

// td_main: tile = 4 sampled points (64 rows) x K=96 (feat 0..63 | xyz 64..66 | 0).
// Register software-pipeline: tile t+1's gathers issued at top of iter t from
// the bf16 table, parked in regs across MFMA+epilogue, written to LDS after B2.
// 6 blocks/CU (VGPR budget ~84 incl. AGPR: 64-reg kernel fits, no spill;
// 8/CU forces 32+32 split and spills catastrophically -- measured R7).
__global__ __launch_bounds__(256, 6) void td_main(
    const float* __restrict__ point, const float* __restrict__ feat,
    const unsigned short* __restrict__ fb, const float* __restrict__ W,
    const float* __restrict__ gamma,
    const int* __restrict__ sample_idx, const int* __restrict__ knn_idx,
    float* __restrict__ ymax_out, float* __restrict__ ymin_out,
    float* __restrict__ partials, int nTiles, int has_ymin, int use_fb)
{
  __shared__ __align__(16) unsigned short A[64 * 104];   // 13312 B
  __shared__ int knn_lds[2][64];

  const int tid  = threadIdx.x;
  const int lane = tid & 63;
  const int wv   = tid >> 6;        // wave -> output channels wv*32..+31
  const int l15  = lane & 15;
  const int lg   = lane >> 4;
  const int G    = gridDim.x;
  const int t0   = blockIdx.x;
  const int segs = (tid & 3) << 4;  // element offset of this thread's 16-elem segment

  // One-time: B fragments direct from global W (bf16-rounded), permuted K.
  short8v bfrag[2][3];
  #pragma unroll
  for (int ni = 0; ni < 2; ++ni) {
    const int d = wv * 32 + ni * 16 + l15;
    #pragma unroll
    for (int kk = 0; kk < 3; ++kk) {
      short8v bf;
      #pragma unroll
      for (int j = 0; j < 8; ++j) {
        int c = kk * 32 + (lg << 3) + j;
        float v = 0.f;
        if (c < 64)      v = W[(3 + c) * 128 + d];
        else if (c < 67) v = W[(c - 64) * 128 + d];
        bf[j] = (short)f2bf(v);
      }
      bfrag[ni][kk] = bf;
    }
  }
  // min-path only needed for channels with gamma<0 (sign(a)==sign(gamma))
  const float gva = gamma[wv * 32 + l15];
  const float gvb = gamma[wv * 32 + 16 + l15];
  const bool  do_min = has_ymin && (__ballot((gva < 0.f) || (gvb < 0.f)) != 0ull);

  const bool alive = (t0 < nTiles);
  if (alive && tid < 64) knn_lds[0][tid] = knn_idx[t0 * 64 + tid];
  __syncthreads();

  // pipeline registers
  uint4v h0 = {0,0,0,0}, h1 = {0,0,0,0};
  float qx = 0, qy = 0, qz = 0, sx = 0, sy = 0, sz = 0;
  int   si_a = 0, knn_next = 0;

  // tile t0 loads (dependent chain once, in prologue)
  if (alive) {
    const int grow = knn_lds[0][tid >> 2];
    if (use_fb) {
      const uint4v* src = (const uint4v*)(fb + ((size_t)grow << 6) + segs);
      h0 = src[0]; h1 = src[1];
    } else {
      const float* srcf = feat + ((size_t)grow << 6) + segs;
      float4v f0 = *(const float4v*)(srcf),     f1 = *(const float4v*)(srcf + 4);
      float4v f2 = *(const float4v*)(srcf + 8), f3 = *(const float4v*)(srcf + 12);
      h0[0] = pk2(f0[0], f0[1]); h0[1] = pk2(f0[2], f0[3]);
      h0[2] = pk2(f1[0], f1[1]); h0[3] = pk2(f1[2], f1[3]);
      h1[0] = pk2(f2[0], f2[1]); h1[1] = pk2(f2[2], f2[3]);
      h1[2] = pk2(f3[0], f3[1]); h1[3] = pk2(f3[2], f3[3]);
    }
    if (tid < 64) {
      const float* ps = point + (unsigned)knn_lds[0][tid] * 3u;
      qx = ps[0]; qy = ps[1]; qz = ps[2];
      int si = sample_idx[t0 * 4 + (tid >> 4)];
      const float* pp2 = point + (unsigned)si * 3u;
      sx = pp2[0]; sy = pp2[1]; sz = pp2[2];
    }
  }
  if (t0 + G < nTiles && tid < 64) {
    knn_lds[1][tid] = knn_idx[(t0 + G) * 64 + tid];
    si_a = sample_idx[(t0 + G) * 4 + (tid >> 4)];
  }

  // write A[t0] (incl. one-time zero of cols 72..95)
  if (alive) {
    unsigned short* dst = A + (tid >> 2) * 104 + segs;
    *(uint4v*)(dst)     = h0;
    *(uint4v*)(dst + 8) = h1;
    if (tid < 64) {
      uint4v u; u[0] = pk2(qx - sx, qy - sy); u[1] = pk2(qz - sz, 0.f);
      u[2] = 0u; u[3] = 0u;
      unsigned short* dx = A + tid * 104 + 64;
      *(uint4v*)(dx) = u;                         // cols 64..71
      uint4v zz = {0u, 0u, 0u, 0u};
      *(uint4v*)(dx + 8)  = zz;                   // cols 72..95: once
      *(uint4v*)(dx + 16) = zz;
      *(uint4v*)(dx + 24) = zz;
    }
  }

  float sum0 = 0.f, sum1 = 0.f, sq0 = 0.f, sq1 = 0.f;

  int b = 0;
  for (int t = t0; t < nTiles; t += G, b ^= 1) {
    __syncthreads();   // B1: A[t] ready; knn[b^1] (tile t+G) visible
    const int tn  = t + G;
    const int tnn = t + 2 * G;
    const bool have_next = (tn < nTiles);

    // issue tile t+1 loads into regs (fly across MFMA + epilogue)
    if (have_next) {
      const int grow = knn_lds[b ^ 1][tid >> 2];
      if (use_fb) {
        const uint4v* src = (const uint4v*)(fb + ((size_t)grow << 6) + segs);
        h0 = src[0]; h1 = src[1];
      } else {
        const float* srcf = feat + ((size_t)grow << 6) + segs;
        float4v f0 = *(const float4v*)(srcf),     f1 = *(const float4v*)(srcf + 4);
        float4v f2 = *(const float4v*)(srcf + 8), f3 = *(const float4v*)(srcf + 12);
        h0[0] = pk2(f0[0], f0[1]); h0[1] = pk2(f0[2], f0[3]);
        h0[2] = pk2(f1[0], f1[1]); h0[3] = pk2(f1[2], f1[3]);
        h1[0] = pk2(f2[0], f2[1]); h1[1] = pk2(f2[2], f2[3]);
        h1[2] = pk2(f3[0], f3[1]); h1[3] = pk2(f3[2], f3[3]);
      }
      if (tid < 64) {
        const float* ps = point + (unsigned)knn_lds[b ^ 1][tid] * 3u;
        qx = ps[0]; qy = ps[1]; qz = ps[2];
        const float* pp2 = point + (unsigned)si_a * 3u;  // si_a from last iter
        sx = pp2[0]; sy = pp2[1]; sz = pp2[2];
      }
    }
    // issue tile t+2 index loads
    if (tnn < nTiles && tid < 64) {
      knn_next = knn_idx[tnn * 64 + tid];
      si_a = sample_idx[tnn * 4 + (tid >> 4)];
    }

    // MFMA on A[t]
    float4v acc[4][2];
    #pragma unroll
    for (int mi = 0; mi < 4; ++mi) {
      acc[mi][0] = (float4v){0.f, 0.f, 0.f, 0.f};
      acc[mi][1] = (float4v){0.f, 0.f, 0.f, 0.f};
    }
    #pragma unroll
    for (int mi = 0; mi < 4; ++mi) {
      const unsigned short* ar = A + (mi * 16 + l15) * 104 + (lg << 3);
      short8v a0 = *(const short8v*)(ar);
      short8v a1 = *(const short8v*)(ar + 32);
      short8v a2 = *(const short8v*)(ar + 64);
      #pragma unroll
      for (int ni = 0; ni < 2; ++ni) {
        acc[mi][ni] = __builtin_amdgcn_mfma_f32_16x16x32_bf16(a0, bfrag[ni][0], acc[mi][ni], 0, 0, 0);
        acc[mi][ni] = __builtin_amdgcn_mfma_f32_16x16x32_bf16(a1, bfrag[ni][1], acc[mi][ni], 0, 0, 0);
        acc[mi][ni] = __builtin_amdgcn_mfma_f32_16x16x32_bf16(a2, bfrag[ni][2], acc[mi][ni], 0, 0, 0);
      }
    }

    // epilogue: stats + per-point max (min only if some gamma<0)
    float mx0[4], mx1[4], mn0[4], mn1[4];
    #pragma unroll
    for (int mi = 0; mi < 4; ++mi) {
      #pragma unroll
      for (int ni = 0; ni < 2; ++ni) {
        float4v v = acc[mi][ni];
        float s = (v[0] + v[1]) + (v[2] + v[3]);
        float q = fmaf(v[0], v[0], fmaf(v[1], v[1], fmaf(v[2], v[2], v[3] * v[3])));
        if (ni == 0) { sum0 += s; sq0 += q; } else { sum1 += s; sq1 += q; }
        float mx = fmaxf(fmaxf(v[0], v[1]), fmaxf(v[2], v[3]));
        mx = fmaxf(mx, __shfl_xor(mx, 16)); mx = fmaxf(mx, __shfl_xor(mx, 32));
        if (ni == 0) mx0[mi] = mx; else mx1[mi] = mx;
        if (do_min) {
          float mn = fminf(fminf(v[0], v[1]), fminf(v[2], v[3]));
          mn = fminf(mn, __shfl_xor(mn, 16)); mn = fminf(mn, __shfl_xor(mn, 32));
          if (ni == 0) mn0[mi] = mn; else mn1[mi] = mn;
        }
      }
    }
    {
      float vx0 = lg == 0 ? mx0[0] : lg == 1 ? mx0[1] : lg == 2 ? mx0[2] : mx0[3];
      float vx1 = lg == 0 ? mx1[0] : lg == 1 ? mx1[1] : lg == 2 ? mx1[2] : mx1[3];
      size_t obase = (size_t)(t * 4 + lg) * 128 + wv * 32 + l15;
      ymax_out[obase]      = vx0;
      ymax_out[obase + 16] = vx1;
      if (do_min) {
        float vn0 = lg == 0 ? mn0[0] : lg == 1 ? mn0[1] : lg == 2 ? mn0[2] : mn0[3];
        float vn1 = lg == 0 ? mn1[0] : lg == 1 ? mn1[1] : lg == 2 ? mn1[2] : mn1[3];
        if (gva < 0.f) ymin_out[obase]      = vn0;
        if (gvb < 0.f) ymin_out[obase + 16] = vn1;
      }
    }
    // park prefetched knn for t+2 (loads long completed)
    if (tnn < nTiles && tid < 64) knn_lds[b][tid] = knn_next;
    __syncthreads();   // B2: A[t] consumed

    // write A[t+1] from in-flight regs (cols 0..71; 72..95 stay zero)
    if (have_next) {
      unsigned short* dst = A + (tid >> 2) * 104 + segs;
      *(uint4v*)(dst)     = h0;
      *(uint4v*)(dst + 8) = h1;
      if (tid < 64) {
        uint4v u; u[0] = pk2(qx - sx, qy - sy); u[1] = pk2(qz - sz, 0.f);
        u[2] = 0u; u[3] = 0u;
        *(uint4v*)(A + tid * 104 + 64) = u;
      }
    }
  }

  // deterministic per-block partials
  sum0 += __shfl_xor(sum0, 16); sum0 += __shfl_xor(sum0, 32);
  sq0  += __shfl_xor(sq0, 16);  sq0  += __shfl_xor(sq0, 32);
  sum1 += __shfl_xor(sum1, 16); sum1 += __shfl_xor(sum1, 32);
  sq1  += __shfl_xor(sq1, 16);  sq1  += __shfl_xor(sq1, 32);
  if (lane < 16) {
    float* pp = partials + (size_t)blockIdx.x * 256;
    pp[wv * 32 + lane]            = sum0;
    pp[128 + wv * 32 + lane]      = sq0;
    pp[wv * 32 + 16 + lane]       = sum1;
    pp[128 + wv * 32 + 16 + lane] = sq1;
  }
}

// Parallel BN-stats fold: one block per channel.
__global__ __launch_bounds__(256) void td_stats(
    const float* __restrict__ partials,
    const float* __restrict__ gamma,
    const float* __restrict__ beta,
    float* __restrict__ ab, int G, float invN)
{
  __shared__ float ls[256], lq[256];
  const int d = blockIdx.x;
  const int t = threadIdx.x;
  float s = 0.f, q = 0.f;
  for (int g = t; g < G; g += 256) {
    s += partials[(size_t)g * 256 + d];
    q += partials[(size_t)g * 256 + 128 + d];
  }
  ls[t] = s; lq[t] = q;
  __syncthreads();
  for (int w = 128; w > 0; w >>= 1) {
    if (t < w) { ls[t] += ls[t + w]; lq[t] += lq[t + w]; }
    __syncthreads();
  }
  if (t == 0) {
    float mean = ls[0] * invN;
    float var  = fmaxf(lq[0] * invN - mean * mean, 0.f);
    float a = gamma[d] * rsqrtf(var + 1e-5f);
    float bb = beta[d] - mean * a;
    ab[d] = a;
    ab[128 + d] = bb;
  }
}

__global__ __launch_bounds__(256) void td_transform(
    float* __restrict__ outf, const float* __restrict__ ymin,
    const float* __restrict__ ab, int total4, int has_ymin)
{
  __shared__ float sab[256];
  __shared__ int s_anyneg;
  sab[threadIdx.x] = ab[threadIdx.x];
  if (threadIdx.x == 0) s_anyneg = 0;
  __syncthreads();
  if (threadIdx.x < 128 && sab[threadIdx.x] < 0.f) s_anyneg = 1;
  __syncthreads();
  const int need_min = has_ymin && s_anyneg;
  int stride = gridDim.x * blockDim.x;
  for (int i = blockIdx.x * blockDim.x + threadIdx.x; i < total4; i += stride) {
    float4v v = *(const float4v*)(outf + (size_t)i * 4);
    int d0 = (i * 4) & 127;
    if (need_min) {
      float4v mn = *(const float4v*)(ymin + (size_t)i * 4);
      #pragma unroll
      for (int j = 0; j < 4; ++j)
        if (sab[d0 + j] < 0.f) v[j] = mn[j];
    }
    #pragma unroll
    for (int j = 0; j < 4; ++j) {
      float z = fmaf(v[j], sab[d0 + j], sab[128 + d0 + j]);
      v[j] = z > 0.f ? z : 0.f;
    }
    *(float4v*)(outf + (size_t)i * 4) = v;
  }
}

extern "C" void kernel_launch(void* const* d_in, const int* in_sizes, int n_in,
                              void* d_out, int out_size, void* d_ws, size_t ws_size,
                              hipStream_t stream)
{
  const float* point = (const float*)d_in[0];
  const float* feat  = (const float*)d_in[1];
  const float* W     = (const float*)d_in[2];
  const float* gamma = (const float*)d_in[3];
  const float* beta  = (const float*)d_in[4];
  const int* sample_idx = (const int*)d_in[5];
  const int* knn_idx    = (const int*)d_in[6];

  const int m = in_sizes[5];            // 60000
  const int k = in_sizes[6] / m;        // 16
  const int nTiles = m / 4;             // 4 points (64 rows) per tile
  const int feat_elems = in_sizes[1];   // n * 64

  float* out  = (float*)d_out;
  float* newp = out;                    // (m,3)
  float* ymax = out + (size_t)m * 3;    // (m,128) pre-norm max, finished in-place

  // 10 tiles/block -> G=1500 for m=60000: fits one resident generation at
  // 6 blocks/CU (1536 capacity) and divides nTiles exactly (uniform work).
  int G = (nTiles + 9) / 10;
  if (G > 1536) G = 1536;
  if (G < 1) G = 1;

  // ws layout: [ab 1KB][partials G*1KB][feat_bf16][ymin if it fits]
  char* ws = (char*)d_ws;
  float* ab = (float*)ws;
  float* partials = (float*)(ws + 1024);
  size_t fb_off = 1024 + (size_t)G * 1024;
  size_t fb_bytes = (size_t)feat_elems * 2;
  int use_fb = (ws_size >= fb_off + fb_bytes) ? 1 : 0;
  unsigned short* fb = (unsigned short*)(ws + fb_off);
  size_t ymin_off = fb_off + (use_fb ? fb_bytes : 0);
  int has_ymin = (ws_size >= ymin_off + (size_t)m * 512) ? 1 : 0;
  float* ymin = (float*)(ws + ymin_off);

  {
    int total8 = use_fb ? feat_elems / 8 : 0;
    int prepBlocks = (total8 + 255) / 256;
    int npBlocks = (m + 255) / 256;
    td_prep<<<prepBlocks + npBlocks, 256, 0, stream>>>(
        feat, fb, total8, point, sample_idx, newp, m, prepBlocks);
  }
  td_main<<<G, 256, 0, stream>>>(point, feat, fb, W, gamma, sample_idx, knn_idx,
                                 ymax, ymin, partials, nTiles, has_ymin, use_fb);
  float invN = 1.0f / ((float)m * (float)k);
  td_stats<<<128, 256, 0, stream>>>(partials, gamma, beta, ab, G, invN);
  td_transform<<<2048, 256, 0, stream>>>(ymax, ymin, ab, m * 128 / 4, has_ymin);
}

// Round 10
// 120.066 us; speedup vs baseline: 2.1637x; 1.3848x over previous
//
#include <hip/hip_runtime.h>
#include <hip/hip_bf16.h>

typedef __attribute__((ext_vector_type(4))) float float4v;
typedef __attribute__((ext_vector_type(8))) short short8v;
typedef __attribute__((ext_vector_type(4))) unsigned int uint4v;

__device__ __forceinline__ unsigned short f2bf(float f) {
  __hip_bfloat16 h = __float2bfloat16(f);
  return __builtin_bit_cast(unsigned short, h);
}
__device__ __forceinline__ unsigned int pk2(float a, float b) {
  return (unsigned int)f2bf(a) | ((unsigned int)f2bf(b) << 16);
}

// Fused one-time pass: feat f32 -> bf16 table + new_point copy.
__global__ __launch_bounds__(256) void td_prep(const float* __restrict__ feat,
                                               unsigned short* __restrict__ fb,
                                               int total8,
                                               const float* __restrict__ point,
                                               const int* __restrict__ sidx,
                                               float* __restrict__ newp, int m,
                                               int prepBlocks) {
  if ((int)blockIdx.x < prepBlocks) {
    int i = blockIdx.x * 256 + threadIdx.x;
    if (i < total8) {
      const float4v a = *(const float4v*)(feat + (size_t)i * 8);
      const float4v c = *(const float4v*)(feat + (size_t)i * 8 + 4);
      uint4v u;
      u[0] = pk2(a[0], a[1]); u[1] = pk2(a[2], a[3]);
      u[2] = pk2(c[0], c[1]); u[3] = pk2(c[2], c[3]);
      *(uint4v*)(fb + (size_t)i * 8) = u;
    }
  } else {
    int i = (blockIdx.x - prepBlocks) * 256 + threadIdx.x;
    if (i < m) {
      unsigned s = (unsigned)sidx[i];
      newp[(size_t)i * 3 + 0] = point[s * 3u + 0];
      newp[(size_t)i * 3 + 1] = point[s * 3u + 1];
      newp[(size_t)i * 3 + 2] = point[s * 3u + 2];
    }
  }
}

// td_main: tile = 4 sampled points (64 rows) x K=96 (feat 0..63 | xyz 64..66 | 0).
// DEPTH-2 register pipeline: tile t+2's gathers issued at top of iter t,
// parked in one of two ping-ponged staging sets (2x-unrolled loop, static reg
// roles), written to LDS two phases later. Indices prefetched 1 phase ahead in
// registers. 4 blocks/CU: 64+32 acc regs fit; 6-8/CU spills (R7/R8 measured).
__global__ __launch_bounds__(256, 4) void td_main(
    const float* __restrict__ point, const float* __restrict__ feat,
    const unsigned short* __restrict__ fb, const float* __restrict__ W,
    const float* __restrict__ gamma,
    const int* __restrict__ sample_idx, const int* __restrict__ knn_idx,
    float* __restrict__ ymax_out, float* __restrict__ ymin_out,
    float* __restrict__ partials, int nTiles, int has_ymin, int use_fb)
{
  __shared__ __align__(16) unsigned short A[64 * 104];   // 13312 B

  const int tid  = threadIdx.x;
  const int lane = tid & 63;
  const int wv   = tid >> 6;
  const int l15  = lane & 15;
  const int lg   = lane >> 4;
  const int G    = gridDim.x;
  const int t0   = blockIdx.x;
  const int segs = (tid & 3) << 4;
  const int r4   = tid >> 2;

  // B fragments direct from global W (bf16-rounded), permuted K.
  short8v bfrag[2][3];
  #pragma unroll
  for (int ni = 0; ni < 2; ++ni) {
    const int d = wv * 32 + ni * 16 + l15;
    #pragma unroll
    for (int kk = 0; kk < 3; ++kk) {
      short8v bf;
      #pragma unroll
      for (int j = 0; j < 8; ++j) {
        int c = kk * 32 + (lg << 3) + j;
        float v = 0.f;
        if (c < 64)      v = W[(3 + c) * 128 + d];
        else if (c < 67) v = W[(c - 64) * 128 + d];
        bf[j] = (short)f2bf(v);
      }
      bfrag[ni][kk] = bf;
    }
  }
  const float gva = gamma[wv * 32 + l15];
  const float gvb = gamma[wv * 32 + 16 + l15];
  const bool  do_min = has_ymin && (__ballot((gva < 0.f) || (gvb < 0.f)) != 0ull);

  float sum0 = 0.f, sum1 = 0.f, sq0 = 0.f, sq1 = 0.f;

  // ---- staging sets (ping-pong, static roles via 2x unroll) ----
  uint4v h0a = {0,0,0,0}, h1a = {0,0,0,0}, h0b = {0,0,0,0}, h1b = {0,0,0,0};
  float qxa=0,qya=0,qza=0,sxa=0,sya=0,sza=0;
  float qxb=0,qyb=0,qzb=0,sxb=0,syb=0,szb=0;
  int kr_a=0,kq_a=0,ks_a=0, kr_b=0,kq_b=0,ks_b=0;

#define ISSUE(SUF, KR, KQ, KS)                                                  \
  do {                                                                          \
    if (use_fb) {                                                               \
      const uint4v* src_ = (const uint4v*)(fb + ((size_t)(KR) << 6) + segs);    \
      h0##SUF = src_[0]; h1##SUF = src_[1];                                     \
    } else {                                                                    \
      const float* sf_ = feat + ((size_t)(KR) << 6) + segs;                     \
      float4v f0_ = *(const float4v*)(sf_),      f1_ = *(const float4v*)(sf_+4);\
      float4v f2_ = *(const float4v*)(sf_ + 8),  f3_ = *(const float4v*)(sf_+12);\
      h0##SUF[0]=pk2(f0_[0],f0_[1]); h0##SUF[1]=pk2(f0_[2],f0_[3]);             \
      h0##SUF[2]=pk2(f1_[0],f1_[1]); h0##SUF[3]=pk2(f1_[2],f1_[3]);             \
      h1##SUF[0]=pk2(f2_[0],f2_[1]); h1##SUF[1]=pk2(f2_[2],f2_[3]);             \
      h1##SUF[2]=pk2(f3_[0],f3_[1]); h1##SUF[3]=pk2(f3_[2],f3_[3]);             \
    }                                                                           \
    if (tid < 64) {                                                             \
      const float* ps_ = point + (unsigned)(KQ) * 3u;                           \
      qx##SUF = ps_[0]; qy##SUF = ps_[1]; qz##SUF = ps_[2];                     \
      const float* pp_ = point + (unsigned)(KS) * 3u;                           \
      sx##SUF = pp_[0]; sy##SUF = pp_[1]; sz##SUF = pp_[2];                     \
    }                                                                           \
  } while (0)

#define AWRITE(SUF)                                                             \
  do {                                                                          \
    unsigned short* dst_ = A + r4 * 104 + segs;                                 \
    *(uint4v*)(dst_)     = h0##SUF;                                             \
    *(uint4v*)(dst_ + 8) = h1##SUF;                                             \
    if (tid < 64) {                                                             \
      uint4v u_; u_[0] = pk2(qx##SUF - sx##SUF, qy##SUF - sy##SUF);             \
      u_[1] = pk2(qz##SUF - sz##SUF, 0.f); u_[2] = 0u; u_[3] = 0u;              \
      *(uint4v*)(A + tid * 104 + 64) = u_;                                      \
    }                                                                           \
  } while (0)

#define IDXLOAD(KR, KQ, KS, TT)                                                 \
  do {                                                                          \
    KR = knn_idx[(TT) * 64 + r4];                                               \
    if (tid < 64) {                                                             \
      KQ = knn_idx[(TT) * 64 + tid];                                            \
      KS = sample_idx[(TT) * 4 + (tid >> 4)];                                   \
    }                                                                           \
  } while (0)

  // ---------------- prologue ----------------
  {
    const int t1 = t0 + G, t2 = t0 + 2 * G;
    int kr0=0,kq0=0,ks0=0, kr1=0,kq1=0,ks1=0;
    IDXLOAD(kr0, kq0, ks0, t0);
    if (t1 < nTiles) IDXLOAD(kr1, kq1, ks1, t1);
    if (t2 < nTiles) IDXLOAD(kr_a, kq_a, ks_a, t2);
    ISSUE(a, kr0, kq0, ks0);
    AWRITE(a);
    {   // one-time zero of cols 72..95 (R9 bug: 72..79 was missed)
      uint4v zz = {0u,0u,0u,0u};
      if (tid < 64) {
        *(uint4v*)(A + tid * 104 + 72) = zz;   // cols 72..79
        *(uint4v*)(A + tid * 104 + 80) = zz;   // cols 80..87
        *(uint4v*)(A + tid * 104 + 88) = zz;   // cols 88..95
      }
    }
    if (t1 < nTiles) ISSUE(b, kr1, kq1, ks1);
  }

#define SUBSTEP(U, P, Q, KRP, KQP, KSP, KRN, KQN, KSN)                          \
  do {                                                                          \
    const int u_ = (U);                                                         \
    __syncthreads();   /* B1: A[u] ready */                                     \
    const int tnn_ = u_ + 2 * G, tpre_ = u_ + 3 * G, tn_ = u_ + G;              \
    if (tnn_ < nTiles)  ISSUE(P, KRP, KQP, KSP);                                \
    if (tpre_ < nTiles) IDXLOAD(KRN, KQN, KSN, tpre_);                          \
    float4v acc[4][2];                                                          \
    _Pragma("unroll")                                                           \
    for (int mi = 0; mi < 4; ++mi) {                                            \
      acc[mi][0] = (float4v){0.f,0.f,0.f,0.f};                                  \
      acc[mi][1] = (float4v){0.f,0.f,0.f,0.f};                                  \
    }                                                                           \
    _Pragma("unroll")                                                           \
    for (int mi = 0; mi < 4; ++mi) {                                            \
      const unsigned short* ar_ = A + (mi * 16 + l15) * 104 + (lg << 3);        \
      short8v a0_ = *(const short8v*)(ar_);                                     \
      short8v a1_ = *(const short8v*)(ar_ + 32);                                \
      short8v a2_ = *(const short8v*)(ar_ + 64);                                \
      _Pragma("unroll")                                                         \
      for (int ni = 0; ni < 2; ++ni) {                                          \
        acc[mi][ni] = __builtin_amdgcn_mfma_f32_16x16x32_bf16(a0_, bfrag[ni][0], acc[mi][ni], 0, 0, 0); \
        acc[mi][ni] = __builtin_amdgcn_mfma_f32_16x16x32_bf16(a1_, bfrag[ni][1], acc[mi][ni], 0, 0, 0); \
        acc[mi][ni] = __builtin_amdgcn_mfma_f32_16x16x32_bf16(a2_, bfrag[ni][2], acc[mi][ni], 0, 0, 0); \
      }                                                                         \
    }                                                                           \
    float mx0_[4], mx1_[4], mn0_[4], mn1_[4];                                   \
    _Pragma("unroll")                                                           \
    for (int mi = 0; mi < 4; ++mi) {                                            \
      _Pragma("unroll")                                                         \
      for (int ni = 0; ni < 2; ++ni) {                                          \
        float4v v_ = acc[mi][ni];                                               \
        float s_ = (v_[0] + v_[1]) + (v_[2] + v_[3]);                           \
        float q_ = fmaf(v_[0],v_[0], fmaf(v_[1],v_[1], fmaf(v_[2],v_[2], v_[3]*v_[3]))); \
        if (ni == 0) { sum0 += s_; sq0 += q_; } else { sum1 += s_; sq1 += q_; } \
        float mx_ = fmaxf(fmaxf(v_[0],v_[1]), fmaxf(v_[2],v_[3]));              \
        mx_ = fmaxf(mx_, __shfl_xor(mx_, 16)); mx_ = fmaxf(mx_, __shfl_xor(mx_, 32)); \
        if (ni == 0) mx0_[mi] = mx_; else mx1_[mi] = mx_;                       \
        if (do_min) {                                                           \
          float mn_ = fminf(fminf(v_[0],v_[1]), fminf(v_[2],v_[3]));            \
          mn_ = fminf(mn_, __shfl_xor(mn_, 16)); mn_ = fminf(mn_, __shfl_xor(mn_, 32)); \
          if (ni == 0) mn0_[mi] = mn_; else mn1_[mi] = mn_;                     \
        }                                                                       \
      }                                                                         \
    }                                                                           \
    {                                                                           \
      float vx0_ = lg==0 ? mx0_[0] : lg==1 ? mx0_[1] : lg==2 ? mx0_[2] : mx0_[3]; \
      float vx1_ = lg==0 ? mx1_[0] : lg==1 ? mx1_[1] : lg==2 ? mx1_[2] : mx1_[3]; \
      size_t ob_ = (size_t)(u_ * 4 + lg) * 128 + wv * 32 + l15;                 \
      ymax_out[ob_]      = vx0_;                                                \
      ymax_out[ob_ + 16] = vx1_;                                                \
      if (do_min) {                                                             \
        float vn0_ = lg==0 ? mn0_[0] : lg==1 ? mn0_[1] : lg==2 ? mn0_[2] : mn0_[3]; \
        float vn1_ = lg==0 ? mn1_[0] : lg==1 ? mn1_[1] : lg==2 ? mn1_[2] : mn1_[3]; \
        if (gva < 0.f) ymin_out[ob_]      = vn0_;                               \
        if (gvb < 0.f) ymin_out[ob_ + 16] = vn1_;                               \
      }                                                                         \
    }                                                                           \
    __syncthreads();   /* B2: A[u] consumed */                                  \
    if (tn_ < nTiles) AWRITE(Q);                                                \
  } while (0)

  for (int u = t0; u < nTiles; u += 2 * G) {
    SUBSTEP(u,     a, b, kr_a, kq_a, ks_a, kr_b, kq_b, ks_b);
    if (u + G < nTiles)
      SUBSTEP(u + G, b, a, kr_b, kq_b, ks_b, kr_a, kq_a, ks_a);
  }

  // deterministic per-block partials
  sum0 += __shfl_xor(sum0, 16); sum0 += __shfl_xor(sum0, 32);
  sq0  += __shfl_xor(sq0, 16);  sq0  += __shfl_xor(sq0, 32);
  sum1 += __shfl_xor(sum1, 16); sum1 += __shfl_xor(sum1, 32);
  sq1  += __shfl_xor(sq1, 16);  sq1  += __shfl_xor(sq1, 32);
  if (lane < 16) {
    float* pp = partials + (size_t)blockIdx.x * 256;
    pp[wv * 32 + lane]            = sum0;
    pp[128 + wv * 32 + lane]      = sq0;
    pp[wv * 32 + 16 + lane]       = sum1;
    pp[128 + wv * 32 + 16 + lane] = sq1;
  }
#undef ISSUE
#undef AWRITE
#undef IDXLOAD
#undef SUBSTEP
}

// Parallel BN-stats fold: one block per channel.
__global__ __launch_bounds__(256) void td_stats(
    const float* __restrict__ partials,
    const float* __restrict__ gamma,
    const float* __restrict__ beta,
    float* __restrict__ ab, int G, float invN)
{
  __shared__ float ls[256], lq[256];
  const int d = blockIdx.x;
  const int t = threadIdx.x;
  float s = 0.f, q = 0.f;
  for (int g = t; g < G; g += 256) {
    s += partials[(size_t)g * 256 + d];
    q += partials[(size_t)g * 256 + 128 + d];
  }
  ls[t] = s; lq[t] = q;
  __syncthreads();
  for (int w = 128; w > 0; w >>= 1) {
    if (t < w) { ls[t] += ls[t + w]; lq[t] += lq[t + w]; }
    __syncthreads();
  }
  if (t == 0) {
    float mean = ls[0] * invN;
    float var  = fmaxf(lq[0] * invN - mean * mean, 0.f);
    float a = gamma[d] * rsqrtf(var + 1e-5f);
    float bb = beta[d] - mean * a;
    ab[d] = a;
    ab[128 + d] = bb;
  }
}

__global__ __launch_bounds__(256) void td_transform(
    float* __restrict__ outf, const float* __restrict__ ymin,
    const float* __restrict__ ab, int total4, int has_ymin)
{
  __shared__ float sab[256];
  __shared__ int s_anyneg;
  sab[threadIdx.x] = ab[threadIdx.x];
  if (threadIdx.x == 0) s_anyneg = 0;
  __syncthreads();
  if (threadIdx.x < 128 && sab[threadIdx.x] < 0.f) s_anyneg = 1;
  __syncthreads();
  const int need_min = has_ymin && s_anyneg;
  int stride = gridDim.x * blockDim.x;
  for (int i = blockIdx.x * blockDim.x + threadIdx.x; i < total4; i += stride) {
    float4v v = *(const float4v*)(outf + (size_t)i * 4);
    int d0 = (i * 4) & 127;
    if (need_min) {
      float4v mn = *(const float4v*)(ymin + (size_t)i * 4);
      #pragma unroll
      for (int j = 0; j < 4; ++j)
        if (sab[d0 + j] < 0.f) v[j] = mn[j];
    }
    #pragma unroll
    for (int j = 0; j < 4; ++j) {
      float z = fmaf(v[j], sab[d0 + j], sab[128 + d0 + j]);
      v[j] = z > 0.f ? z : 0.f;
    }
    *(float4v*)(outf + (size_t)i * 4) = v;
  }
}

extern "C" void kernel_launch(void* const* d_in, const int* in_sizes, int n_in,
                              void* d_out, int out_size, void* d_ws, size_t ws_size,
                              hipStream_t stream)
{
  const float* point = (const float*)d_in[0];
  const float* feat  = (const float*)d_in[1];
  const float* W     = (const float*)d_in[2];
  const float* gamma = (const float*)d_in[3];
  const float* beta  = (const float*)d_in[4];
  const int* sample_idx = (const int*)d_in[5];
  const int* knn_idx    = (const int*)d_in[6];

  const int m = in_sizes[5];            // 60000
  const int k = in_sizes[6] / m;        // 16
  const int nTiles = m / 4;
  const int feat_elems = in_sizes[1];   // n * 64

  float* out  = (float*)d_out;
  float* newp = out;                    // (m,3)
  float* ymax = out + (size_t)m * 3;    // (m,128)

  int G = (nTiles + 7) / 8;             // 8 tiles/block (R6 geometry)
  if (G > 2048) G = 2048;
  if (G < 1) G = 1;

  // ws layout: [ab 1KB][partials G*1KB][feat_bf16][ymin if it fits]
  char* ws = (char*)d_ws;
  float* ab = (float*)ws;
  float* partials = (float*)(ws + 1024);
  size_t fb_off = 1024 + (size_t)G * 1024;
  size_t fb_bytes = (size_t)feat_elems * 2;
  int use_fb = (ws_size >= fb_off + fb_bytes) ? 1 : 0;
  unsigned short* fb = (unsigned short*)(ws + fb_off);
  size_t ymin_off = fb_off + (use_fb ? fb_bytes : 0);
  int has_ymin = (ws_size >= ymin_off + (size_t)m * 512) ? 1 : 0;
  float* ymin = (float*)(ws + ymin_off);

  {
    int total8 = use_fb ? feat_elems / 8 : 0;
    int prepBlocks = (total8 + 255) / 256;
    int npBlocks = (m + 255) / 256;
    td_prep<<<prepBlocks + npBlocks, 256, 0, stream>>>(
        feat, fb, total8, point, sample_idx, newp, m, prepBlocks);
  }
  td_main<<<G, 256, 0, stream>>>(point, feat, fb, W, gamma, sample_idx, knn_idx,
                                 ymax, ymin, partials, nTiles, has_ymin, use_fb);
  float invN = 1.0f / ((float)m * (float)k);
  td_stats<<<128, 256, 0, stream>>>(partials, gamma, beta, ab, G, invN);
  td_transform<<<2048, 256, 0, stream>>>(ymax, ymin, ab, m * 128 / 4, has_ymin);
}

// Round 11
// 104.566 us; speedup vs baseline: 2.4845x; 1.1482x over previous
//
#include <hip/hip_runtime.h>
#include <hip/hip_bf16.h>

typedef __attribute__((ext_vector_type(4))) float float4v;
typedef __attribute__((ext_vector_type(8))) short short8v;
typedef __attribute__((ext_vector_type(4))) unsigned int uint4v;

__device__ __forceinline__ unsigned short f2bf(float f) {
  __hip_bfloat16 h = __float2bfloat16(f);
  return __builtin_bit_cast(unsigned short, h);
}
__device__ __forceinline__ unsigned int pk2(float a, float b) {
  return (unsigned int)f2bf(a) | ((unsigned int)f2bf(b) << 16);
}

// Fused one-time pass: feat f32 -> bf16 table + new_point copy.
__global__ __launch_bounds__(256) void td_prep(const float* __restrict__ feat,
                                               unsigned short* __restrict__ fb,
                                               int total8,
                                               const float* __restrict__ point,
                                               const int* __restrict__ sidx,
                                               float* __restrict__ newp, int m,
                                               int prepBlocks) {
  if ((int)blockIdx.x < prepBlocks) {
    int i = blockIdx.x * 256 + threadIdx.x;
    if (i < total8) {
      const float4v a = *(const float4v*)(feat + (size_t)i * 8);
      const float4v c = *(const float4v*)(feat + (size_t)i * 8 + 4);
      uint4v u;
      u[0] = pk2(a[0], a[1]); u[1] = pk2(a[2], a[3]);
      u[2] = pk2(c[0], c[1]); u[3] = pk2(c[2], c[3]);
      *(uint4v*)(fb + (size_t)i * 8) = u;
    }
  } else {
    int i = (blockIdx.x - prepBlocks) * 256 + threadIdx.x;
    if (i < m) {
      unsigned s = (unsigned)sidx[i];
      newp[(size_t)i * 3 + 0] = point[s * 3u + 0];
      newp[(size_t)i * 3 + 1] = point[s * 3u + 1];
      newp[(size_t)i * 3 + 2] = point[s * 3u + 2];
    }
  }
}

// td_main: tile = 4 sampled points (64 rows) x K=96 (feat 0..63 | xyz 64..66 | 0).
// LDS double-buffered pipeline, ONE barrier per tile:
//   barrier; AWRITE(h -> A[nxt]); ISSUE(t+2) -> h; IDXLOAD(t+3); MFMA(A[cur]).
// Single register staging set (R10's second set spilled: WRITE 104MB scratch).
__global__ __launch_bounds__(256, 4) void td_main(
    const float* __restrict__ point, const float* __restrict__ feat,
    const unsigned short* __restrict__ fb, const float* __restrict__ W,
    const float* __restrict__ gamma,
    const int* __restrict__ sample_idx, const int* __restrict__ knn_idx,
    float* __restrict__ ymax_out, float* __restrict__ ymin_out,
    float* __restrict__ partials, int nTiles, int has_ymin, int use_fb)
{
  __shared__ __align__(16) unsigned short A0[64 * 104];   // 13312 B each
  __shared__ __align__(16) unsigned short A1[64 * 104];

  const int tid  = threadIdx.x;
  const int lane = tid & 63;
  const int wv   = tid >> 6;
  const int l15  = lane & 15;
  const int lg   = lane >> 4;
  const int G    = gridDim.x;
  const int t0   = blockIdx.x;
  const int segs = (tid & 3) << 4;
  const int r4   = tid >> 2;

  // B fragments direct from global W (bf16-rounded), permuted K.
  short8v bfrag[2][3];
  #pragma unroll
  for (int ni = 0; ni < 2; ++ni) {
    const int d = wv * 32 + ni * 16 + l15;
    #pragma unroll
    for (int kk = 0; kk < 3; ++kk) {
      short8v bf;
      #pragma unroll
      for (int j = 0; j < 8; ++j) {
        int c = kk * 32 + (lg << 3) + j;
        float v = 0.f;
        if (c < 64)      v = W[(3 + c) * 128 + d];
        else if (c < 67) v = W[(c - 64) * 128 + d];
        bf[j] = (short)f2bf(v);
      }
      bfrag[ni][kk] = bf;
    }
  }
  const float gva = gamma[wv * 32 + l15];
  const float gvb = gamma[wv * 32 + 16 + l15];
  const bool  do_min = has_ymin && (__ballot((gva < 0.f) || (gvb < 0.f)) != 0ull);

  float sum0 = 0.f, sum1 = 0.f, sq0 = 0.f, sq1 = 0.f;

  // single staging set (regs): h0,h1 = feat row quarter; q/s = xyz points
  uint4v h0 = {0,0,0,0}, h1 = {0,0,0,0};
  float qx=0,qy=0,qz=0,sx=0,sy=0,sz=0;
  // idx ping-pong (prefetched one full iteration ahead)
  int kr_a=0,kq_a=0,ks_a=0, kr_b=0,kq_b=0,ks_b=0;

#define IDXLOAD(KR, KQ, KS, TT)                                                 \
  do {                                                                          \
    KR = knn_idx[(TT) * 64 + r4];                                               \
    if (tid < 64) {                                                             \
      KQ = knn_idx[(TT) * 64 + tid];                                            \
      KS = sample_idx[(TT) * 4 + (tid >> 4)];                                   \
    }                                                                           \
  } while (0)

#define ISSUE(KR, KQ, KS)                                                       \
  do {                                                                          \
    if (use_fb) {                                                               \
      const uint4v* src_ = (const uint4v*)(fb + ((size_t)(KR) << 6) + segs);    \
      h0 = src_[0]; h1 = src_[1];                                               \
    } else {                                                                    \
      const float* sf_ = feat + ((size_t)(KR) << 6) + segs;                     \
      float4v f0_ = *(const float4v*)(sf_),      f1_ = *(const float4v*)(sf_+4);\
      float4v f2_ = *(const float4v*)(sf_ + 8),  f3_ = *(const float4v*)(sf_+12);\
      h0[0]=pk2(f0_[0],f0_[1]); h0[1]=pk2(f0_[2],f0_[3]);                       \
      h0[2]=pk2(f1_[0],f1_[1]); h0[3]=pk2(f1_[2],f1_[3]);                       \
      h1[0]=pk2(f2_[0],f2_[1]); h1[1]=pk2(f2_[2],f2_[3]);                       \
      h1[2]=pk2(f3_[0],f3_[1]); h1[3]=pk2(f3_[2],f3_[3]);                       \
    }                                                                           \
    if (tid < 64) {                                                             \
      const float* ps_ = point + (unsigned)(KQ) * 3u;                           \
      qx = ps_[0]; qy = ps_[1]; qz = ps_[2];                                    \
      const float* pp_ = point + (unsigned)(KS) * 3u;                           \
      sx = pp_[0]; sy = pp_[1]; sz = pp_[2];                                    \
    }                                                                           \
  } while (0)

#define AWRITE(BUF)                                                             \
  do {                                                                          \
    unsigned short* dst_ = BUF + r4 * 104 + segs;                               \
    *(uint4v*)(dst_)     = h0;                                                  \
    *(uint4v*)(dst_ + 8) = h1;                                                  \
    if (tid < 64) {                                                             \
      uint4v u_; u_[0] = pk2(qx - sx, qy - sy);                                 \
      u_[1] = pk2(qz - sz, 0.f); u_[2] = 0u; u_[3] = 0u;                        \
      *(uint4v*)(BUF + tid * 104 + 64) = u_;                                    \
    }                                                                           \
  } while (0)

  // ---------------- prologue ----------------
  {
    int kr0=0,kq0=0,ks0=0;
    IDXLOAD(kr0, kq0, ks0, t0);
    ISSUE(kr0, kq0, ks0);              // dependent chain once
    AWRITE(A0);                        // tile t0 -> A0
    {                                  // zero pads of BOTH buffers, once
      uint4v zz = {0u,0u,0u,0u};
      if (tid < 64) {
        *(uint4v*)(A0 + tid * 104 + 72) = zz;
        *(uint4v*)(A0 + tid * 104 + 80) = zz;
        *(uint4v*)(A0 + tid * 104 + 88) = zz;
        *(uint4v*)(A1 + tid * 104 + 72) = zz;
        *(uint4v*)(A1 + tid * 104 + 80) = zz;
        *(uint4v*)(A1 + tid * 104 + 88) = zz;
      }
    }
    if (t0 + G < nTiles) {             // tile t1 -> staging regs (in flight)
      IDXLOAD(kr0, kq0, ks0, t0 + G);
      ISSUE(kr0, kq0, ks0);
    }
    if (t0 + 2 * G < nTiles)           // idx for tile t2
      IDXLOAD(kr_a, kq_a, ks_a, t0 + 2 * G);
  }

// One tile step: compute tile U from CURBUF; publish tile U+1 (h) into NXTBUF;
// start gather of tile U+2 (using idx pair P); prefetch idx of tile U+3 into N.
#define STEP(U, CURBUF, NXTBUF, KRP, KQP, KSP, KRN, KQN, KSN)                   \
  do {                                                                          \
    const int u_ = (U);                                                         \
    __syncthreads();   /* publishes CURBUF (tile u); frees NXTBUF */            \
    if (u_ + G < nTiles)     AWRITE(NXTBUF);                                    \
    if (u_ + 2 * G < nTiles) ISSUE(KRP, KQP, KSP);                              \
    if (u_ + 3 * G < nTiles) IDXLOAD(KRN, KQN, KSN, u_ + 3 * G);                \
    float4v acc[4][2];                                                          \
    _Pragma("unroll")                                                           \
    for (int mi = 0; mi < 4; ++mi) {                                            \
      acc[mi][0] = (float4v){0.f,0.f,0.f,0.f};                                  \
      acc[mi][1] = (float4v){0.f,0.f,0.f,0.f};                                  \
    }                                                                           \
    _Pragma("unroll")                                                           \
    for (int mi = 0; mi < 4; ++mi) {                                            \
      const unsigned short* ar_ = CURBUF + (mi * 16 + l15) * 104 + (lg << 3);   \
      short8v a0_ = *(const short8v*)(ar_);                                     \
      short8v a1_ = *(const short8v*)(ar_ + 32);                                \
      short8v a2_ = *(const short8v*)(ar_ + 64);                                \
      _Pragma("unroll")                                                         \
      for (int ni = 0; ni < 2; ++ni) {                                          \
        acc[mi][ni] = __builtin_amdgcn_mfma_f32_16x16x32_bf16(a0_, bfrag[ni][0], acc[mi][ni], 0, 0, 0); \
        acc[mi][ni] = __builtin_amdgcn_mfma_f32_16x16x32_bf16(a1_, bfrag[ni][1], acc[mi][ni], 0, 0, 0); \
        acc[mi][ni] = __builtin_amdgcn_mfma_f32_16x16x32_bf16(a2_, bfrag[ni][2], acc[mi][ni], 0, 0, 0); \
      }                                                                         \
    }                                                                           \
    float mx0_[4], mx1_[4], mn0_[4], mn1_[4];                                   \
    _Pragma("unroll")                                                           \
    for (int mi = 0; mi < 4; ++mi) {                                            \
      _Pragma("unroll")                                                         \
      for (int ni = 0; ni < 2; ++ni) {                                          \
        float4v v_ = acc[mi][ni];                                               \
        float s_ = (v_[0] + v_[1]) + (v_[2] + v_[3]);                           \
        float q_ = fmaf(v_[0],v_[0], fmaf(v_[1],v_[1], fmaf(v_[2],v_[2], v_[3]*v_[3]))); \
        if (ni == 0) { sum0 += s_; sq0 += q_; } else { sum1 += s_; sq1 += q_; } \
        float mx_ = fmaxf(fmaxf(v_[0],v_[1]), fmaxf(v_[2],v_[3]));              \
        mx_ = fmaxf(mx_, __shfl_xor(mx_, 16)); mx_ = fmaxf(mx_, __shfl_xor(mx_, 32)); \
        if (ni == 0) mx0_[mi] = mx_; else mx1_[mi] = mx_;                       \
        if (do_min) {                                                           \
          float mn_ = fminf(fminf(v_[0],v_[1]), fminf(v_[2],v_[3]));            \
          mn_ = fminf(mn_, __shfl_xor(mn_, 16)); mn_ = fminf(mn_, __shfl_xor(mn_, 32)); \
          if (ni == 0) mn0_[mi] = mn_; else mn1_[mi] = mn_;                     \
        }                                                                       \
      }                                                                         \
    }                                                                           \
    {                                                                           \
      float vx0_ = lg==0 ? mx0_[0] : lg==1 ? mx0_[1] : lg==2 ? mx0_[2] : mx0_[3]; \
      float vx1_ = lg==0 ? mx1_[0] : lg==1 ? mx1_[1] : lg==2 ? mx1_[2] : mx1_[3]; \
      size_t ob_ = (size_t)(u_ * 4 + lg) * 128 + wv * 32 + l15;                 \
      ymax_out[ob_]      = vx0_;                                                \
      ymax_out[ob_ + 16] = vx1_;                                                \
      if (do_min) {                                                             \
        float vn0_ = lg==0 ? mn0_[0] : lg==1 ? mn0_[1] : lg==2 ? mn0_[2] : mn0_[3]; \
        float vn1_ = lg==0 ? mn1_[0] : lg==1 ? mn1_[1] : lg==2 ? mn1_[2] : mn1_[3]; \
        if (gva < 0.f) ymin_out[ob_]      = vn0_;                               \
        if (gvb < 0.f) ymin_out[ob_ + 16] = vn1_;                               \
      }                                                                         \
    }                                                                           \
  } while (0)

  for (int u = t0; u < nTiles; u += 2 * G) {
    STEP(u,     A0, A1, kr_a, kq_a, ks_a, kr_b, kq_b, ks_b);
    if (u + G < nTiles)
      STEP(u + G, A1, A0, kr_b, kq_b, ks_b, kr_a, kq_a, ks_a);
  }

  // deterministic per-block partials
  sum0 += __shfl_xor(sum0, 16); sum0 += __shfl_xor(sum0, 32);
  sq0  += __shfl_xor(sq0, 16);  sq0  += __shfl_xor(sq0, 32);
  sum1 += __shfl_xor(sum1, 16); sum1 += __shfl_xor(sum1, 32);
  sq1  += __shfl_xor(sq1, 16);  sq1  += __shfl_xor(sq1, 32);
  if (lane < 16) {
    float* pp = partials + (size_t)blockIdx.x * 256;
    pp[wv * 32 + lane]            = sum0;
    pp[128 + wv * 32 + lane]      = sq0;
    pp[wv * 32 + 16 + lane]       = sum1;
    pp[128 + wv * 32 + 16 + lane] = sq1;
  }
#undef IDXLOAD
#undef ISSUE
#undef AWRITE
#undef STEP
}

// Parallel BN-stats fold: one block per channel.
__global__ __launch_bounds__(256) void td_stats(
    const float* __restrict__ partials,
    const float* __restrict__ gamma,
    const float* __restrict__ beta,
    float* __restrict__ ab, int G, float invN)
{
  __shared__ float ls[256], lq[256];
  const int d = blockIdx.x;
  const int t = threadIdx.x;
  float s = 0.f, q = 0.f;
  for (int g = t; g < G; g += 256) {
    s += partials[(size_t)g * 256 + d];
    q += partials[(size_t)g * 256 + 128 + d];
  }
  ls[t] = s; lq[t] = q;
  __syncthreads();
  for (int w = 128; w > 0; w >>= 1) {
    if (t < w) { ls[t] += ls[t + w]; lq[t] += lq[t + w]; }
    __syncthreads();
  }
  if (t == 0) {
    float mean = ls[0] * invN;
    float var  = fmaxf(lq[0] * invN - mean * mean, 0.f);
    float a = gamma[d] * rsqrtf(var + 1e-5f);
    float bb = beta[d] - mean * a;
    ab[d] = a;
    ab[128 + d] = bb;
  }
}

__global__ __launch_bounds__(256) void td_transform(
    float* __restrict__ outf, const float* __restrict__ ymin,
    const float* __restrict__ ab, int total4, int has_ymin)
{
  __shared__ float sab[256];
  __shared__ int s_anyneg;
  sab[threadIdx.x] = ab[threadIdx.x];
  if (threadIdx.x == 0) s_anyneg = 0;
  __syncthreads();
  if (threadIdx.x < 128 && sab[threadIdx.x] < 0.f) s_anyneg = 1;
  __syncthreads();
  const int need_min = has_ymin && s_anyneg;
  int stride = gridDim.x * blockDim.x;
  for (int i = blockIdx.x * blockDim.x + threadIdx.x; i < total4; i += stride) {
    float4v v = *(const float4v*)(outf + (size_t)i * 4);
    int d0 = (i * 4) & 127;
    if (need_min) {
      float4v mn = *(const float4v*)(ymin + (size_t)i * 4);
      #pragma unroll
      for (int j = 0; j < 4; ++j)
        if (sab[d0 + j] < 0.f) v[j] = mn[j];
    }
    #pragma unroll
    for (int j = 0; j < 4; ++j) {
      float z = fmaf(v[j], sab[d0 + j], sab[128 + d0 + j]);
      v[j] = z > 0.f ? z : 0.f;
    }
    *(float4v*)(outf + (size_t)i * 4) = v;
  }
}

extern "C" void kernel_launch(void* const* d_in, const int* in_sizes, int n_in,
                              void* d_out, int out_size, void* d_ws, size_t ws_size,
                              hipStream_t stream)
{
  const float* point = (const float*)d_in[0];
  const float* feat  = (const float*)d_in[1];
  const float* W     = (const float*)d_in[2];
  const float* gamma = (const float*)d_in[3];
  const float* beta  = (const float*)d_in[4];
  const int* sample_idx = (const int*)d_in[5];
  const int* knn_idx    = (const int*)d_in[6];

  const int m = in_sizes[5];            // 60000
  const int k = in_sizes[6] / m;        // 16
  const int nTiles = m / 4;
  const int feat_elems = in_sizes[1];   // n * 64

  float* out  = (float*)d_out;
  float* newp = out;                    // (m,3)
  float* ymax = out + (size_t)m * 3;    // (m,128)

  int G = (nTiles + 7) / 8;             // 8 tiles/block (R6 geometry)
  if (G > 2048) G = 2048;
  if (G < 1) G = 1;

  // ws layout: [ab 1KB][partials G*1KB][feat_bf16][ymin if it fits]
  char* ws = (char*)d_ws;
  float* ab = (float*)ws;
  float* partials = (float*)(ws + 1024);
  size_t fb_off = 1024 + (size_t)G * 1024;
  size_t fb_bytes = (size_t)feat_elems * 2;
  int use_fb = (ws_size >= fb_off + fb_bytes) ? 1 : 0;
  unsigned short* fb = (unsigned short*)(ws + fb_off);
  size_t ymin_off = fb_off + (use_fb ? fb_bytes : 0);
  int has_ymin = (ws_size >= ymin_off + (size_t)m * 512) ? 1 : 0;
  float* ymin = (float*)(ws + ymin_off);

  {
    int total8 = use_fb ? feat_elems / 8 : 0;
    int prepBlocks = (total8 + 255) / 256;
    int npBlocks = (m + 255) / 256;
    td_prep<<<prepBlocks + npBlocks, 256, 0, stream>>>(
        feat, fb, total8, point, sample_idx, newp, m, prepBlocks);
  }
  td_main<<<G, 256, 0, stream>>>(point, feat, fb, W, gamma, sample_idx, knn_idx,
                                 ymax, ymin, partials, nTiles, has_ymin, use_fb);
  float invN = 1.0f / ((float)m * (float)k);
  td_stats<<<128, 256, 0, stream>>>(partials, gamma, beta, ab, G, invN);
  td_transform<<<2048, 256, 0, stream>>>(ymax, ymin, ab, m * 128 / 4, has_ymin);
}